// Round 1
// 584.560 us; speedup vs baseline: 1.0269x; 1.0269x over previous
//
#include <hip/hip_runtime.h>

#define NNODES 50000
#define NEDGES 800000
#define NNODE_DICT 10000
#define NEDGE_DICT 100
#define EMB 128
#define HID 32
#define HEADS 4
#define DD 128            // HID*HEADS
#define SLOPE 0.2f
#define LN_EPS 1e-5f
#define NEG_BIG -3.0e38f

#define NDICT_BLOCKS (NNODE_DICT / 4)              // 2500
#define EDICT_BLOCKS (NEDGE_DICT)                  // 100
#define COUNT_BLOCKS ((NEDGES / 4 + 127) / 128)    // 1563
#define NTILES ((NNODES + 1023) / 1024)            // 49
#define AGG_BLOCKS ((NNODES + 3) / 4)              // 12500
#define EOUT_BLOCKS (NEDGES * 32 / 256)            // 100000
#define BACK_BLOCKS (AGG_BLOCKS + EOUT_BLOCKS)     // 112500 = 9 * AGG_BLOCKS

typedef float vfloat4 __attribute__((ext_vector_type(4)));

// ---- Fused front: node dict GEMM + edge dict GEMM/LN + degree count ----
// All three are mutually independent; fusing lets the VALU-bound dict
// transforms co-schedule with the latency-bound atomics of count.
__global__ __launch_bounds__(128) void front_kernel(
        const float* __restrict__ node_emb,
        const float* __restrict__ w_W,
        const float* __restrict__ w_b,
        const float* __restrict__ attn,
        float* __restrict__ h_dict,
        float* __restrict__ s_i_d,
        float* __restrict__ s_j_d,
        const float* __restrict__ edge_emb,
        const float* __restrict__ ew_W,
        const float* __restrict__ ew_b,
        const float* __restrict__ gamma,
        const float* __restrict__ beta,
        float* __restrict__ eh2_dict,
        float* __restrict__ s_e_d,
        const int* __restrict__ edge_index,
        int* __restrict__ counts) {
    __shared__ float a_sh[4][EMB];
    __shared__ float red[4];
    int bid = blockIdx.x;
    int col = threadIdx.x;

    if (bid < NDICT_BLOCKS) {
        // ---- node dict transform, 4 rows/block, register tiling ----
        int r0 = bid * 4;
        #pragma unroll
        for (int r = 0; r < 4; ++r) a_sh[r][col] = node_emb[(r0 + r) * EMB + col];
        __syncthreads();
        float acc0 = 0.f, acc1 = 0.f, acc2 = 0.f, acc3 = 0.f;
        #pragma unroll 8
        for (int k = 0; k < EMB; ++k) {
            float wv = w_W[k * DD + col];
            acc0 += a_sh[0][k] * wv;
            acc1 += a_sh[1][k] * wv;
            acc2 += a_sh[2][k] * wv;
            acc3 += a_sh[3][k] * wv;
        }
        float b = w_b[col];
        acc0 += b; acc1 += b; acc2 += b; acc3 += b;
        h_dict[(r0 + 0) * DD + col] = acc0;
        h_dict[(r0 + 1) * DD + col] = acc1;
        h_dict[(r0 + 2) * DD + col] = acc2;
        h_dict[(r0 + 3) * DD + col] = acc3;

        int head = col >> 5, f = col & 31;
        float ai = attn[head * 96 + f];
        float aj = attn[head * 96 + 32 + f];
        float accs[4] = {acc0, acc1, acc2, acc3};
        #pragma unroll
        for (int r = 0; r < 4; ++r) {
            float pi = accs[r] * ai;
            float pj = accs[r] * aj;
            #pragma unroll
            for (int off = 16; off > 0; off >>= 1) {
                pi += __shfl_down(pi, off);
                pj += __shfl_down(pj, off);
            }
            if ((col & 31) == 0) {
                s_i_d[(r0 + r) * HEADS + head] = pi;
                s_j_d[(r0 + r) * HEADS + head] = pj;
            }
        }
    } else if (bid < NDICT_BLOCKS + EDICT_BLOCKS) {
        // ---- edge dict transform + s_e + LayerNorm(eh) per dict row ----
        int row = bid - NDICT_BLOCKS;
        a_sh[0][col] = edge_emb[row * EMB + col];
        __syncthreads();
        float acc = 0.f;
        #pragma unroll 8
        for (int k = 0; k < EMB; ++k) acc += a_sh[0][k] * ew_W[k * DD + col];
        acc += ew_b[col];

        int head = col >> 5, f = col & 31;
        float pe = acc * attn[head * 96 + 64 + f];
        #pragma unroll
        for (int off = 16; off > 0; off >>= 1) pe += __shfl_down(pe, off);
        if ((col & 31) == 0) s_e_d[row * HEADS + head] = pe;

        float s = acc, s2 = acc * acc;
        #pragma unroll
        for (int off = 32; off > 0; off >>= 1) {
            s  += __shfl_down(s, off);
            s2 += __shfl_down(s2, off);
        }
        int wid = col >> 6;
        if ((col & 63) == 0) { red[wid * 2] = s; red[wid * 2 + 1] = s2; }
        __syncthreads();
        s = red[0] + red[2];
        s2 = red[1] + red[3];
        float mu = s * (1.f / DD);
        float var = s2 * (1.f / DD) - mu * mu;
        float r = rsqrtf(var + LN_EPS);
        eh2_dict[row * DD + col] = (acc - mu) * r * gamma[col] + beta[col];
    } else {
        // ---- degree count (int4, 4 edges/thread) ----
        int i = (bid - NDICT_BLOCKS - EDICT_BLOCKS) * 128 + col;
        if (i < NEDGES / 4) {
            int4 t = ((const int4*)edge_index)[i];
            atomicAdd(&counts[t.x], 1);
            atomicAdd(&counts[t.y], 1);
            atomicAdd(&counts[t.z], 1);
            atomicAdd(&counts[t.w], 1);
        }
    }
}

// ---- CSR step 2a: per-tile scan (tile = 1024 elems, 256 thr, 4/thread) ----
__global__ __launch_bounds__(256) void scan_tiles(const int* __restrict__ counts,
                                                  int* __restrict__ excl,
                                                  int* __restrict__ tsums) {
    __shared__ int wred[4];
    int tile = blockIdx.x;
    int tid = threadIdx.x;
    int base = tile * 1024 + tid * 4;
    int4 v = make_int4(0, 0, 0, 0);
    if (base + 3 < NNODES) {
        v = *(const int4*)(counts + base);
    } else {
        if (base + 0 < NNODES) v.x = counts[base + 0];
        if (base + 1 < NNODES) v.y = counts[base + 1];
        if (base + 2 < NNODES) v.z = counts[base + 2];
        if (base + 3 < NNODES) v.w = counts[base + 3];
    }
    int tsum = v.x + v.y + v.z + v.w;
    int lane = tid & 63, w = tid >> 6;
    int incl = tsum;
    #pragma unroll
    for (int o = 1; o < 64; o <<= 1) {
        int t = __shfl_up(incl, o);
        if (lane >= o) incl += t;
    }
    if (lane == 63) wred[w] = incl;
    __syncthreads();
    int wexc = 0;
    #pragma unroll
    for (int j = 0; j < 4; ++j) if (j < w) wexc += wred[j];
    int ex = wexc + incl - tsum;
    int4 o4 = make_int4(ex, ex + v.x, ex + v.x + v.y, ex + v.x + v.y + v.z);
    if (base + 3 < NNODES) {
        *(int4*)(excl + base) = o4;
    } else {
        if (base + 0 < NNODES) excl[base + 0] = o4.x;
        if (base + 1 < NNODES) excl[base + 1] = o4.y;
        if (base + 2 < NNODES) excl[base + 2] = o4.z;
        if (base + 3 < NNODES) excl[base + 3] = o4.w;
    }
    if (tid == 255) tsums[tile] = wexc + incl;   // tile total (unscanned)
}

// ---- CSR step 2b+2c fused: every block redundantly scans the 49 tile
// sums in its first wave (trivial), then adds bases + inits cursor.
// offsets[NNODES] is the constant NEDGES. Removes the scan_sums dispatch. ----
__global__ __launch_bounds__(256) void scan_fixup2(const int* __restrict__ tsums,
                                                   int* __restrict__ offsets,
                                                   int* __restrict__ cursor) {
    __shared__ int sbase[64];
    int tid = threadIdx.x;
    if (tid < 64) {                       // whole wave 0: shfl is safe
        int v = (tid < NTILES) ? tsums[tid] : 0;
        int incl = v;
        #pragma unroll
        for (int o = 1; o < 64; o <<= 1) {
            int t = __shfl_up(incl, o);
            if (tid >= o) incl += t;
        }
        sbase[tid] = incl - v;            // exclusive tile base
    }
    __syncthreads();
    int i = blockIdx.x * 256 + tid;
    if (i < NNODES) {
        int v = offsets[i] + sbase[i >> 10];
        offsets[i] = v;
        cursor[i] = v;
    }
    if (blockIdx.x == 0 && tid == 0) offsets[NNODES] = NEDGES;
}

// ---- CSR step 3: scatter (ns, ee) into CSR order ----
__global__ void scatter_kernel(const int* __restrict__ edge_index,
                               const int* __restrict__ node_features,
                               const int* __restrict__ edge_features,
                               int* __restrict__ cursor,
                               int2* __restrict__ csr) {
    int e = blockIdx.x * blockDim.x + threadIdx.x;
    if (e >= NEDGES) return;
    int tgt = edge_index[e];
    int src = edge_index[NEDGES + e];
    int ns = node_features[src];
    int ee = edge_features[e];
    int pos = atomicAdd(&cursor[tgt], 1);
    csr[pos] = make_int2(ns, ee);
}

// ---- Fused back end: node aggregation (softmax+sum+residual+LN) blocks
// interleaved 1:8 with edge-output (pure write-BW) blocks so the
// latency/VALU-bound agg work overlaps the HBM-write-bound stream for the
// whole dispatch, not just the tail. BACK_BLOCKS = 9 * AGG_BLOCKS exactly. ----
__global__ __launch_bounds__(256) void back_kernel(
        const int* __restrict__ offsets,
        const int2* __restrict__ csr,
        const int* __restrict__ node_features,
        const float4* __restrict__ s_i4,
        const float4* __restrict__ s_j4,
        const float4* __restrict__ s_e4,
        const float* __restrict__ h_dict,
        const float* __restrict__ gamma,
        const float* __restrict__ beta,
        float* __restrict__ out,
        const int* __restrict__ edge_features,
        const vfloat4* __restrict__ eh2_dict4,
        vfloat4* __restrict__ out4) {
    __shared__ float sp[4][256];
    __shared__ int   sns[4][64];
    int bid = blockIdx.x;
    int a = bid / 9;
    int r9 = bid - a * 9;

    if (r9 != 0) {
        // ---- edge output: eh2[e] = eh2_dict[edge_features[e]] ----
        int eb = 8 * a + r9 - 1;                 // [0, EOUT_BLOCKS)
        int t = eb * 256 + threadIdx.x;          // < NEDGES*32 exactly
        int e = t >> 5;                          // 32 float4 per row
        int j = t & 31;
        int ee = edge_features[e];
        vfloat4 v = eh2_dict4[ee * 32 + j];
        __builtin_nontemporal_store(v, out4 + (size_t)t);
        return;
    }

    // ---- node aggregation: one wave per node ----
    int wid = threadIdx.x >> 6;
    int lane = threadIdx.x & 63;
    int n = a * 4 + wid;
    if (n >= NNODES) return;            // no block barriers below: safe

    int nt = node_features[n];
    float4 si = s_i4[nt];
    int off = offsets[n];
    int deg = offsets[n + 1] - off;

    float m0 = NEG_BIG, m1 = NEG_BIG, m2 = NEG_BIG, m3 = NEG_BIG;
    float l0 = 0.f, l1 = 0.f, l2 = 0.f, l3 = 0.f;
    float acc0 = 0.f, acc1 = 0.f;
    int h0 = lane >> 5;            // head of col=lane      (0/1)
    int h1 = 2 + (lane >> 5);      // head of col=lane+64   (2/3)

    for (int base = 0; base < deg; base += 64) {
        int cnt = min(deg - base, 64);
        float4 ev = make_float4(NEG_BIG, NEG_BIG, NEG_BIG, NEG_BIG);
        int ns = 0;
        if (lane < cnt) {
            int2 pr = csr[off + base + lane];
            ns = pr.x;
            float4 sj = s_j4[pr.x];
            float4 se = s_e4[pr.y];
            ev.x = si.x + sj.x + se.x; ev.x = ev.x > 0.f ? ev.x : SLOPE * ev.x;
            ev.y = si.y + sj.y + se.y; ev.y = ev.y > 0.f ? ev.y : SLOPE * ev.y;
            ev.z = si.z + sj.z + se.z; ev.z = ev.z > 0.f ? ev.z : SLOPE * ev.z;
            ev.w = si.w + sj.w + se.w; ev.w = ev.w > 0.f ? ev.w : SLOPE * ev.w;
        }
        // wave max per head
        float4 mv = ev;
        #pragma unroll
        for (int o = 32; o > 0; o >>= 1) {
            mv.x = fmaxf(mv.x, __shfl_xor(mv.x, o));
            mv.y = fmaxf(mv.y, __shfl_xor(mv.y, o));
            mv.z = fmaxf(mv.z, __shfl_xor(mv.z, o));
            mv.w = fmaxf(mv.w, __shfl_xor(mv.w, o));
        }
        float nm0 = fmaxf(m0, mv.x), nm1 = fmaxf(m1, mv.y);
        float nm2 = fmaxf(m2, mv.z), nm3 = fmaxf(m3, mv.w);
        float4 p = make_float4(0.f, 0.f, 0.f, 0.f);
        if (lane < cnt) {
            p.x = __expf(ev.x - nm0);
            p.y = __expf(ev.y - nm1);
            p.z = __expf(ev.z - nm2);
            p.w = __expf(ev.w - nm3);
        }
        // wave sum per head
        float4 sv = p;
        #pragma unroll
        for (int o = 32; o > 0; o >>= 1) {
            sv.x += __shfl_xor(sv.x, o);
            sv.y += __shfl_xor(sv.y, o);
            sv.z += __shfl_xor(sv.z, o);
            sv.w += __shfl_xor(sv.w, o);
        }
        float sc0 = __expf(m0 - nm0), sc1 = __expf(m1 - nm1);
        float sc2 = __expf(m2 - nm2), sc3 = __expf(m3 - nm3);
        l0 = l0 * sc0 + sv.x; l1 = l1 * sc1 + sv.y;
        l2 = l2 * sc2 + sv.z; l3 = l3 * sc3 + sv.w;
        m0 = nm0; m1 = nm1; m2 = nm2; m3 = nm3;
        acc0 *= (lane < 32) ? sc0 : sc1;
        acc1 *= (lane < 32) ? sc2 : sc3;
        // broadcast p/ns via wave-local LDS (same wave: no barrier needed)
        if (lane < cnt) {
            sp[wid][lane * 4 + 0] = p.x;
            sp[wid][lane * 4 + 1] = p.y;
            sp[wid][lane * 4 + 2] = p.z;
            sp[wid][lane * 4 + 3] = p.w;
            sns[wid][lane] = ns;
        }
        int nst = sns[wid][0];
        for (int t = 0; t < cnt; ++t) {
            const float* hr = h_dict + (size_t)nst * DD;
            float w0 = sp[wid][t * 4 + h0];
            float w1 = sp[wid][t * 4 + h1];
            if (t + 1 < cnt) nst = sns[wid][t + 1];
            acc0 += w0 * hr[lane];
            acc1 += w1 * hr[lane + 64];
        }
    }

    float den0 = (lane < 32) ? l0 : l1;
    float den1 = (lane < 32) ? l2 : l3;
    float msg0 = den0 > 0.f ? acc0 / den0 : 0.f;
    float msg1 = den1 > 0.f ? acc1 / den1 : 0.f;
    const float* hres = h_dict + (size_t)nt * DD;
    float v0 = msg0 + hres[lane];
    float v1 = msg1 + hres[lane + 64];
    // LayerNorm over 128 cols, fully in-wave
    float s = v0 + v1, s2 = v0 * v0 + v1 * v1;
    #pragma unroll
    for (int o = 32; o > 0; o >>= 1) {
        s  += __shfl_xor(s, o);
        s2 += __shfl_xor(s2, o);
    }
    float mu = s * (1.f / DD);
    float var = s2 * (1.f / DD) - mu * mu;
    float r = rsqrtf(var + LN_EPS);
    out[(size_t)n * DD + lane]      = (v0 - mu) * r * gamma[lane] + beta[lane];
    out[(size_t)n * DD + lane + 64] = (v1 - mu) * r * gamma[lane + 64] + beta[lane + 64];
}

extern "C" void kernel_launch(void* const* d_in, const int* in_sizes, int n_in,
                              void* d_out, int out_size, void* d_ws, size_t ws_size,
                              hipStream_t stream) {
    const int*   node_features = (const int*)d_in[0];
    const int*   edge_features = (const int*)d_in[1];
    const int*   edge_index    = (const int*)d_in[2];
    const float* node_emb      = (const float*)d_in[3];
    const float* edge_emb      = (const float*)d_in[4];
    const float* w_W           = (const float*)d_in[5];
    const float* w_b           = (const float*)d_in[6];
    const float* ew_W          = (const float*)d_in[7];
    const float* ew_b          = (const float*)d_in[8];
    const float* attn          = (const float*)d_in[9];
    const float* gamma         = (const float*)d_in[10];
    const float* beta          = (const float*)d_in[11];

    float* out_nodes = (float*)d_out;
    float* out_edges = (float*)d_out + (size_t)NNODES * DD;

    // workspace layout (all pieces 16B-aligned)
    char* w = (char*)d_ws;
    float* h_dict   = (float*)w;  w += (size_t)NNODE_DICT * DD * 4;   // 5.12 MB
    float* s_i_d    = (float*)w;  w += (size_t)NNODE_DICT * 4 * 4;    // 160 KB
    float* s_j_d    = (float*)w;  w += (size_t)NNODE_DICT * 4 * 4;    // 160 KB
    float* eh2_dict = (float*)w;  w += (size_t)NEDGE_DICT * DD * 4;   // 51 KB
    float* s_e_d    = (float*)w;  w += (size_t)NEDGE_DICT * 4 * 4;    // 1.6 KB
    int*   counts   = (int*)w;    w += (size_t)NNODES * 4;            // 200 KB
    int*   offsets  = (int*)w;    w += (size_t)(NNODES + 4) * 4;      // 200 KB
    int*   cursor   = (int*)w;    w += (size_t)NNODES * 4;            // 200 KB
    int*   tsums    = (int*)w;    w += (size_t)64 * 4;                // 256 B
    int2*  csr      = (int2*)w;   w += (size_t)NEDGES * 8;            // 6.4 MB

    (void)hipMemsetAsync(counts, 0, (size_t)NNODES * 4, stream);

    front_kernel<<<NDICT_BLOCKS + EDICT_BLOCKS + COUNT_BLOCKS, 128, 0, stream>>>(
        node_emb, w_W, w_b, attn, h_dict, s_i_d, s_j_d,
        edge_emb, ew_W, ew_b, gamma, beta, eh2_dict, s_e_d,
        edge_index, counts);
    scan_tiles<<<NTILES, 256, 0, stream>>>(counts, offsets, tsums);
    scan_fixup2<<<(NNODES + 255) / 256, 256, 0, stream>>>(tsums, offsets, cursor);
    scatter_kernel<<<(NEDGES + 255) / 256, 256, 0, stream>>>(edge_index, node_features,
                                                             edge_features, cursor, csr);
    back_kernel<<<BACK_BLOCKS, 256, 0, stream>>>(offsets, csr, node_features,
                                                 (const float4*)s_i_d,
                                                 (const float4*)s_j_d,
                                                 (const float4*)s_e_d,
                                                 h_dict, gamma, beta, out_nodes,
                                                 edge_features,
                                                 (const vfloat4*)eh2_dict,
                                                 (vfloat4*)out_edges);
}